// Round 5
// baseline (2838.992 us; speedup 1.0000x reference)
//
#include <hip/hip_runtime.h>
#include <cstdint>
#include <cstddef>

#define TT   512
#define BATCH 64
#define HID  1024
#define KDIM 1024

typedef short bf16x8 __attribute__((ext_vector_type(8)));
typedef float f32x4 __attribute__((ext_vector_type(4)));

__device__ __forceinline__ unsigned short f2b(float f) {
    unsigned int u = __float_as_uint(f);
    u = (u + 0x7fffu + ((u >> 16) & 1u)) >> 16;
    return (unsigned short)u;
}

// ---------------------------------------------------------------------------
// init: concat biases, zero h buffers + flags + global rank counter
// ---------------------------------------------------------------------------
__global__ __launch_bounds__(256) void k_init(
    const float* __restrict__ b_ir, const float* __restrict__ b_iz, const float* __restrict__ b_in,
    const float* __restrict__ b_hr, const float* __restrict__ b_hz, const float* __restrict__ b_hn,
    float* __restrict__ bias_x, float* __restrict__ bias_h,
    unsigned short* __restrict__ hbf, int* __restrict__ flags, int* __restrict__ gcnt)
{
    int gid = blockIdx.x * 256 + threadIdx.x;          // grid 64x256 = 16384
    if (gid < HID) {
        bias_x[gid]        = b_ir[gid];
        bias_x[HID + gid]  = b_iz[gid];
        bias_x[2*HID + gid]= b_in[gid];
        bias_h[gid]        = b_hr[gid];
        bias_h[HID + gid]  = b_hz[gid];
        bias_h[2*HID + gid]= b_hn[gid];
    }
    // zero both h bf16 buffers: 2*64*1024 ushorts = 32768 ushort4
    ushort4 z4 = make_ushort4(0, 0, 0, 0);
    ushort4* p = reinterpret_cast<ushort4*>(hbf);
    p[2*gid]   = z4;
    p[2*gid+1] = z4;
    if (gid < 256 * 16) flags[gid] = 0;                // 256 flags, 64B-padded
    if (gid < 16) gcnt[gid] = 0;                       // global rank counter
}

// ---------------------------------------------------------------------------
// transpose W[k][j] (fp32) -> wT[n][k] (bf16), n = gate*1024 + j
// grid (32, 32, 6), block (32, 8)
// ---------------------------------------------------------------------------
__global__ __launch_bounds__(256) void k_trans(
    const float* __restrict__ w0, const float* __restrict__ w1, const float* __restrict__ w2,
    const float* __restrict__ w3, const float* __restrict__ w4, const float* __restrict__ w5,
    unsigned short* __restrict__ wxT, unsigned short* __restrict__ whT)
{
    __shared__ float tile[32][33];
    int z = blockIdx.z;
    const float* src = (z == 0) ? w0 : (z == 1) ? w1 : (z == 2) ? w2
                     : (z == 3) ? w3 : (z == 4) ? w4 : w5;
    unsigned short* dst = (z < 3) ? (wxT + (size_t)z * HID * KDIM)
                                  : (whT + (size_t)(z - 3) * HID * KDIM);
    int kb = blockIdx.x * 32, jb = blockIdx.y * 32;
    int tx = threadIdx.x, ty = threadIdx.y;
    #pragma unroll
    for (int p = 0; p < 4; p++)
        tile[tx][ty + 8*p] = src[(size_t)(kb + ty + 8*p) * HID + jb + tx];
    __syncthreads();
    #pragma unroll
    for (int p = 0; p < 4; p++) {
        int n = jb + ty + 8*p;
        dst[(size_t)n * KDIM + kb + tx] = f2b(tile[ty + 8*p][tx]);
    }
}

// ---------------------------------------------------------------------------
// GEMM A: gates = x @ [W_ir|W_iz|W_in] + bias.  M=32768, N=3072, K=1024.
// ---------------------------------------------------------------------------
#define BM 128
#define BN 128
#define LDA 72   // 64 + 8 pad, in ushorts (144 B rows, 16B-aligned)

__global__ __launch_bounds__(256, 2) void k_gemm_x(
    const float* __restrict__ x,            // [32768][1024] fp32
    const unsigned short* __restrict__ wxT, // [3072][1024] bf16
    const float* __restrict__ biasx,        // [3072]
    float* __restrict__ ggr, float* __restrict__ ggz, float* __restrict__ ggn)
{
    __shared__ unsigned short lA[BM * LDA];
    __shared__ unsigned short lB[BN * LDA];
    int tid  = threadIdx.x;
    int wave = tid >> 6, lane = tid & 63;
    int l16  = lane & 15, lhi = lane >> 4;
    int rbase = blockIdx.x * BM;
    int nbase = blockIdx.y * BN;
    int wm = (wave >> 1) * 64, wn = (wave & 1) * 64;

    f32x4 acc[4][4];
    for (int a = 0; a < 4; a++)
        for (int b = 0; b < 4; b++)
            acc[a][b] = f32x4{0.f, 0.f, 0.f, 0.f};

    int arow = tid >> 4;          // 16 rows/pass, 8 passes
    int acol = (tid & 15) * 4;    // float4 within 64 floats
    int brow = tid >> 3;          // 32 rows/pass, 4 passes
    int bcol = (tid & 7) * 8;     // 8 shorts within 64

    for (int kb = 0; kb < KDIM; kb += 64) {
        __syncthreads();
        #pragma unroll
        for (int p = 0; p < 8; p++) {
            int r = p * 16 + arow;
            float4 v = *(const float4*)(x + (size_t)(rbase + r) * KDIM + kb + acol);
            ushort4 s;
            s.x = f2b(v.x); s.y = f2b(v.y); s.z = f2b(v.z); s.w = f2b(v.w);
            *(ushort4*)(lA + r * LDA + acol) = s;
        }
        #pragma unroll
        for (int p = 0; p < 4; p++) {
            int r = p * 32 + brow;
            bf16x8 v = *(const bf16x8*)(wxT + (size_t)(nbase + r) * KDIM + kb + bcol);
            *(bf16x8*)(lB + r * LDA + bcol) = v;
        }
        __syncthreads();
        #pragma unroll
        for (int kk = 0; kk < 2; kk++) {
            bf16x8 af[4], bfr[4];
            #pragma unroll
            for (int mt = 0; mt < 4; mt++)
                af[mt] = *(const bf16x8*)(lA + (wm + mt*16 + l16) * LDA + kk*32 + lhi*8);
            #pragma unroll
            for (int nt = 0; nt < 4; nt++)
                bfr[nt] = *(const bf16x8*)(lB + (wn + nt*16 + l16) * LDA + kk*32 + lhi*8);
            #pragma unroll
            for (int mt = 0; mt < 4; mt++)
                #pragma unroll
                for (int nt = 0; nt < 4; nt++)
                    acc[mt][nt] = __builtin_amdgcn_mfma_f32_16x16x32_bf16(
                        af[mt], bfr[nt], acc[mt][nt], 0, 0, 0);
        }
    }
    // epilogue: C/D layout col=lane&15 (N), row=(lane>>4)*4+i (M)
    #pragma unroll
    for (int nt = 0; nt < 4; nt++) {
        int n = nbase + wn + nt*16 + l16;
        float bv = biasx[n];
        int g = n >> 10;
        int j = n & 1023;
        float* outp = (g == 0) ? ggr : (g == 1) ? ggz : ggn;
        #pragma unroll
        for (int mt = 0; mt < 4; mt++) {
            #pragma unroll
            for (int i = 0; i < 4; i++) {
                int R = rbase + wm + mt*16 + lhi*4 + i;        // R = b*512 + t
                size_t orow = (size_t)((R & 511) * BATCH + (R >> 9));
                outp[orow * HID + j] = acc[mt][nt][i] + bv;
            }
        }
    }
}

// ---------------------------------------------------------------------------
// Recurrence v4: LOGICAL groups, proven LLC (agent-scope) exchange.
//
// 256 blocks self-assign a global rank (one atomicAdd): group g = grank>>5
// (8 groups), rank = grank&31.  Group g owns batch rows [8g, 8g+8); rank r
// owns cols [32r, 32r+32).  Correct for ANY dispatch placement (unlike the
// failed physical-XCD v3b).  h exchange uses the R0/R1-PROVEN agent-scope
// atomic path (LLC): absmax 0.0059 there.
//
// Why faster than R1: the recurrence is LLC-BANDWIDTH-bound on h reads
// (R1: 1024 waves x 8KB = 8 MB/step ~ 3.2us at ~2.5TB/s = the 4.15us step).
// 8 rows/block instead of 16 halves that to 4 MB/step.  MFMA A rows 8..15
// duplicate rows 0..7 (same-address lanes coalesce -> no extra LLC traffic).
// Weight pinning (asm "+v") stops the remat re-fetch (~24 MB/step of L1/L2)
// that VGPR_Count=88<96 exposed in R0/R1.  Group-local polling: wave w polls
// its 8 producers; 4 waves cover all 32 group flags (anti-overrun for the
// parity double-buffer).  Poll guard -> wrongness fails absmax, not a hang.
// ---------------------------------------------------------------------------
__global__ __launch_bounds__(256, 1) void k_recur(
    const float* __restrict__ ggr, const float* __restrict__ ggz,
    float* __restrict__ dout,                // [T][B][H] (gn preloaded) + tail [B][H]
    const unsigned short* __restrict__ whT,  // [3072][1024] bf16
    const float* __restrict__ biash,         // [3072]
    unsigned short* __restrict__ hbf,        // [2][64][1024] bf16
    int* __restrict__ flags,                 // [256] stride-16 ints (64 B lines)
    int* __restrict__ gcnt)                  // global rank counter
{
    __shared__ f32x4 red[6 * 4 * 64];            // 24 KB: (gate*2+ct), wave, lane
    __shared__ unsigned long long hsu[64];       // 512 B: 8x32 bf16 h tile
    __shared__ int shr[1];
    unsigned short* hsp = (unsigned short*)hsu;

    int tid  = threadIdx.x;
    if (tid == 0) shr[0] = atomicAdd(gcnt, 1);
    __syncthreads();
    int grank = shr[0];
    int grp   = (grank >> 5) & 7;  // batch-row group (rows 8g..8g+8)
    int rank  = grank & 31;        // column group (cols 32r..32r+32)

    int w    = tid >> 6, lane = tid & 63;
    int l16  = lane & 15, lhi = lane >> 4;
    int row  = tid >> 5;           // epilogue row 0..7  (batch within group)
    int col  = tid & 31;           // epilogue col 0..31
    int colbase = rank * 32;
    int b_t  = grp * 8 + row;      // epilogue thread's batch row
    int j_t  = colbase + col;      // epilogue thread's column
    int hrow = grp * 8 + (l16 & 7);// mfma A-row (rows 8..15 duplicate 0..7)
    int kbase = w * 256 + lhi * 8; // this lane's K base

    // loop-invariant weight fragments: 2 col-tiles x 3 gates x 8 kk = 192 VGPR
    bf16x8 wf[2][3][8];
    #pragma unroll
    for (int ct = 0; ct < 2; ct++)
        #pragma unroll
        for (int g = 0; g < 3; g++) {
            const unsigned short* base =
                whT + (size_t)(g * HID + colbase + ct * 16 + l16) * KDIM + kbase;
            #pragma unroll
            for (int kk = 0; kk < 8; kk++)
                wf[ct][g][kk] = *(const bf16x8*)(base + kk * 32);
        }
    // pin: def becomes non-rematerializable asm -> stays in VGPRs across loop
    #pragma unroll
    for (int ct = 0; ct < 2; ct++)
        #pragma unroll
        for (int g = 0; g < 3; g++)
            #pragma unroll
            for (int kk = 0; kk < 8; kk++)
                asm volatile("" : "+v"(wf[ct][g][kk]));

    float bhr = biash[j_t], bhz = biash[HID + j_t], bhn = biash[2*HID + j_t];

    float hp = 0.f;
    float cgr, cgz, cgn;
    {
        size_t g0 = (size_t)b_t * HID + j_t;    // t = 0
        cgr = ggr[g0]; cgz = ggz[g0]; cgn = dout[g0];
    }

    // this wave's 8 producers: ranks [8w, 8w+8) of OUR group
    int* pollp  = flags + (size_t)(grp * 32 + w * 8 + (lane & 7)) * 16;
    int* myflag = flags + (size_t)(grp * 32 + rank) * 16;

    #pragma unroll 1
    for (int t = 0; t < TT; t++) {
        // ---- wait for step-t h from this wave's 8 same-group producers ----
        if (t > 0) {
            int guard = 0;
            bool ok;
            do {
                int f = __hip_atomic_load(pollp, __ATOMIC_RELAXED, __HIP_MEMORY_SCOPE_AGENT);
                ok = (f >= t);
            } while (!__all(ok) && ++guard < (1 << 17));
        }

        // ---- h loads: 8 rows x this wave's K-quarter, LLC (agent scope) ----
        const unsigned short* hb = hbf + (size_t)(t & 1) * BATCH * HID
                                 + (size_t)hrow * HID + kbase;
        unsigned long long hu[16];
        #pragma unroll
        for (int kk = 0; kk < 8; kk++) {
            hu[2*kk]   = __hip_atomic_load((unsigned long long*)(hb + kk*32),
                                           __ATOMIC_RELAXED, __HIP_MEMORY_SCOPE_AGENT);
            hu[2*kk+1] = __hip_atomic_load((unsigned long long*)(hb + kk*32) + 1,
                                           __ATOMIC_RELAXED, __HIP_MEMORY_SCOPE_AGENT);
        }

        // ---- gate prefetch for t+1 (plain cached loads, overlap compute) ----
        float ngr = 0.f, ngz = 0.f, ngn = 0.f;
        if (t + 1 < TT) {
            size_t g1 = (size_t)((t + 1) * BATCH + b_t) * HID + j_t;
            ngr = ggr[g1]; ngz = ggz[g1]; ngn = dout[g1];
        }

        // ---- partial GEMM over this wave's K-quarter: 2 col-tiles x 3 gates ----
        f32x4 acc[2][3];
        #pragma unroll
        for (int ct = 0; ct < 2; ct++)
            #pragma unroll
            for (int g = 0; g < 3; g++)
                acc[ct][g] = f32x4{0.f, 0.f, 0.f, 0.f};
        #pragma unroll
        for (int kk = 0; kk < 8; kk++) {
            union { unsigned long long u[2]; bf16x8 v; } fa;
            fa.u[0] = hu[2*kk]; fa.u[1] = hu[2*kk+1];
            #pragma unroll
            for (int ct = 0; ct < 2; ct++)
                #pragma unroll
                for (int g = 0; g < 3; g++)
                    acc[ct][g] = __builtin_amdgcn_mfma_f32_16x16x32_bf16(
                        fa.v, wf[ct][g][kk], acc[ct][g], 0, 0, 0);
        }

        // ---- cross-wave K reduction via LDS ----
        #pragma unroll
        for (int ct = 0; ct < 2; ct++)
            #pragma unroll
            for (int g = 0; g < 3; g++)
                red[((g * 2 + ct) * 4 + w) * 64 + lane] = acc[ct][g];
        __syncthreads();
        int ctt = col >> 4, ri = row & 3;
        int lsrc = (row >> 2) * 16 + (col & 15);
        float s0 = 0.f, s1 = 0.f, s2 = 0.f;
        #pragma unroll
        for (int ww = 0; ww < 4; ww++) {
            s0 += red[((0 * 2 + ctt) * 4 + ww) * 64 + lsrc][ri];
            s1 += red[((1 * 2 + ctt) * 4 + ww) * 64 + lsrc][ri];
            s2 += red[((2 * 2 + ctt) * 4 + ww) * 64 + lsrc][ri];
        }

        // ---- epilogue: one element per thread ----
        float r  = 1.f / (1.f + __expf(-(cgr + s0 + bhr)));
        float z  = 1.f / (1.f + __expf(-(cgz + s1 + bhz)));
        float nv = cgn + r * (s2 + bhn);
        float th = 1.f - 2.f / (1.f + __expf(2.f * nv));   // tanh(nv)
        float hv = (1.f - z) * th + z * hp;
        hp = hv;
        dout[((size_t)t * BATCH + b_t) * HID + j_t] = hv;  // plain store (private)
        if (t == TT - 1) {
            dout[(size_t)TT * BATCH * HID + (size_t)b_t * HID + j_t] = hv;
            break;                                         // no one consumes next h
        }
        cgr = ngr; cgz = ngz; cgn = ngn;

        // ---- publish h tile (8x32) via LLC, then flag ----
        hsp[row * 32 + col] = f2b(hv);
        __syncthreads();
        if (tid < 64) {
            int rr = tid >> 3, ch = tid & 7;
            unsigned long long v = hsu[rr * 8 + ch];
            unsigned long long* dst = (unsigned long long*)(
                hbf + (size_t)((t + 1) & 1) * BATCH * HID
                    + (size_t)(grp * 8 + rr) * HID + colbase + ch * 4);
            __hip_atomic_store(dst, v, __ATOMIC_RELAXED, __HIP_MEMORY_SCOPE_AGENT);
            asm volatile("s_waitcnt vmcnt(0)" ::: "memory");  // h acked at LLC
            if (tid == 0)
                __hip_atomic_store(myflag, t + 1,
                                   __ATOMIC_RELAXED, __HIP_MEMORY_SCOPE_AGENT);
        }
        // no trailing barrier: waves 1-3 are already polling for step t+1
    }
}

// ---------------------------------------------------------------------------
extern "C" void kernel_launch(void* const* d_in, const int* in_sizes, int n_in,
                              void* d_out, int out_size, void* d_ws, size_t ws_size,
                              hipStream_t stream)
{
    const float* x    = (const float*)d_in[0];
    const float* W_ir = (const float*)d_in[1];
    const float* b_ir = (const float*)d_in[2];
    const float* W_hr = (const float*)d_in[3];
    const float* b_hr = (const float*)d_in[4];
    const float* W_iz = (const float*)d_in[5];
    const float* b_iz = (const float*)d_in[6];
    const float* W_hz = (const float*)d_in[7];
    const float* b_hz = (const float*)d_in[8];
    const float* W_in = (const float*)d_in[9];
    const float* b_in = (const float*)d_in[10];
    const float* W_hn = (const float*)d_in[11];
    const float* b_hn = (const float*)d_in[12];
    float* out = (float*)d_out;

    char* ws = (char*)d_ws;
    size_t off = 0;
    auto alloc = [&](size_t bytes) -> char* {
        char* p = ws + off;
        off += (bytes + 255) & ~(size_t)255;
        return p;
    };
    float*          ggr      = (float*)alloc((size_t)TT * BATCH * HID * 4);
    float*          ggz      = (float*)alloc((size_t)TT * BATCH * HID * 4);
    unsigned short* wxT      = (unsigned short*)alloc((size_t)3 * HID * KDIM * 2);
    unsigned short* whT      = (unsigned short*)alloc((size_t)3 * HID * KDIM * 2);
    float*          bias_x   = (float*)alloc(3 * HID * 4);
    float*          bias_h   = (float*)alloc(3 * HID * 4);
    unsigned short* hbf      = (unsigned short*)alloc((size_t)2 * BATCH * HID * 2);
    int*            flags    = (int*)alloc(256 * 16 * 4);
    int*            gcnt     = (int*)alloc(16 * 4);

    k_init<<<64, 256, 0, stream>>>(b_ir, b_iz, b_in, b_hr, b_hz, b_hn,
                                   bias_x, bias_h, hbf, flags, gcnt);
    k_trans<<<dim3(32, 32, 6), dim3(32, 8), 0, stream>>>(W_ir, W_iz, W_in,
                                                         W_hr, W_hz, W_hn, wxT, whT);
    k_gemm_x<<<dim3(256, 24), 256, 0, stream>>>(x, wxT, bias_x, ggr, ggz, out);
    k_recur<<<256, 256, 0, stream>>>(ggr, ggz, out, whT, bias_h, hbf, flags, gcnt);
}

// Round 8
// 2644.427 us; speedup vs baseline: 1.0736x; 1.0736x over previous
//
#include <hip/hip_runtime.h>
#include <cstdint>
#include <cstddef>

#define TT   512
#define BATCH 64
#define HID  1024
#define KDIM 1024

typedef short bf16x8 __attribute__((ext_vector_type(8)));
typedef float f32x4 __attribute__((ext_vector_type(4)));

__device__ __forceinline__ unsigned short f2b(float f) {
    unsigned int u = __float_as_uint(f);
    u = (u + 0x7fffu + ((u >> 16) & 1u)) >> 16;
    return (unsigned short)u;
}

// ---------------------------------------------------------------------------
// init: concat biases, zero h buffers + replicated flags + rank counter
// ---------------------------------------------------------------------------
__global__ __launch_bounds__(256) void k_init(
    const float* __restrict__ b_ir, const float* __restrict__ b_iz, const float* __restrict__ b_in,
    const float* __restrict__ b_hr, const float* __restrict__ b_hz, const float* __restrict__ b_hn,
    float* __restrict__ bias_x, float* __restrict__ bias_h,
    unsigned short* __restrict__ hbf, int* __restrict__ flags2, int* __restrict__ gcnt)
{
    int gid = blockIdx.x * 256 + threadIdx.x;          // grid 64x256 = 16384
    if (gid < HID) {
        bias_x[gid]        = b_ir[gid];
        bias_x[HID + gid]  = b_iz[gid];
        bias_x[2*HID + gid]= b_in[gid];
        bias_h[gid]        = b_hr[gid];
        bias_h[HID + gid]  = b_hz[gid];
        bias_h[2*HID + gid]= b_hn[gid];
    }
    // zero both h bf16 buffers: 2*64*1024 ushorts = 32768 ushort4
    ushort4 z4 = make_ushort4(0, 0, 0, 0);
    ushort4* p = reinterpret_cast<ushort4*>(hbf);
    p[2*gid]   = z4;
    p[2*gid+1] = z4;
    if (gid < 8 * 32 * 32) flags2[gid] = 0;            // replicated flags
    if (gid < 16) gcnt[gid] = 0;                       // global rank counter
}

// ---------------------------------------------------------------------------
// transpose W[k][j] (fp32) -> wT[n][k] (bf16), n = gate*1024 + j
// grid (32, 32, 6), block (32, 8)
// ---------------------------------------------------------------------------
__global__ __launch_bounds__(256) void k_trans(
    const float* __restrict__ w0, const float* __restrict__ w1, const float* __restrict__ w2,
    const float* __restrict__ w3, const float* __restrict__ w4, const float* __restrict__ w5,
    unsigned short* __restrict__ wxT, unsigned short* __restrict__ whT)
{
    __shared__ float tile[32][33];
    int z = blockIdx.z;
    const float* src = (z == 0) ? w0 : (z == 1) ? w1 : (z == 2) ? w2
                     : (z == 3) ? w3 : (z == 4) ? w4 : w5;
    unsigned short* dst = (z < 3) ? (wxT + (size_t)z * HID * KDIM)
                                  : (whT + (size_t)(z - 3) * HID * KDIM);
    int kb = blockIdx.x * 32, jb = blockIdx.y * 32;
    int tx = threadIdx.x, ty = threadIdx.y;
    #pragma unroll
    for (int p = 0; p < 4; p++)
        tile[tx][ty + 8*p] = src[(size_t)(kb + ty + 8*p) * HID + jb + tx];
    __syncthreads();
    #pragma unroll
    for (int p = 0; p < 4; p++) {
        int n = jb + ty + 8*p;
        dst[(size_t)n * KDIM + kb + tx] = f2b(tile[ty + 8*p][tx]);
    }
}

// ---------------------------------------------------------------------------
// GEMM A: gates = x @ [W_ir|W_iz|W_in] + bias.  M=32768, N=3072, K=1024.
// ---------------------------------------------------------------------------
#define BM 128
#define BN 128
#define LDA 72   // 64 + 8 pad, in ushorts (144 B rows, 16B-aligned)

__global__ __launch_bounds__(256, 2) void k_gemm_x(
    const float* __restrict__ x,            // [32768][1024] fp32
    const unsigned short* __restrict__ wxT, // [3072][1024] bf16
    const float* __restrict__ biasx,        // [3072]
    float* __restrict__ ggr, float* __restrict__ ggz, float* __restrict__ ggn)
{
    __shared__ unsigned short lA[BM * LDA];
    __shared__ unsigned short lB[BN * LDA];
    int tid  = threadIdx.x;
    int wave = tid >> 6, lane = tid & 63;
    int l16  = lane & 15, lhi = lane >> 4;
    int rbase = blockIdx.x * BM;
    int nbase = blockIdx.y * BN;
    int wm = (wave >> 1) * 64, wn = (wave & 1) * 64;

    f32x4 acc[4][4];
    for (int a = 0; a < 4; a++)
        for (int b = 0; b < 4; b++)
            acc[a][b] = f32x4{0.f, 0.f, 0.f, 0.f};

    int arow = tid >> 4;          // 16 rows/pass, 8 passes
    int acol = (tid & 15) * 4;    // float4 within 64 floats
    int brow = tid >> 3;          // 32 rows/pass, 4 passes
    int bcol = (tid & 7) * 8;     // 8 shorts within 64

    for (int kb = 0; kb < KDIM; kb += 64) {
        __syncthreads();
        #pragma unroll
        for (int p = 0; p < 8; p++) {
            int r = p * 16 + arow;
            float4 v = *(const float4*)(x + (size_t)(rbase + r) * KDIM + kb + acol);
            ushort4 s;
            s.x = f2b(v.x); s.y = f2b(v.y); s.z = f2b(v.z); s.w = f2b(v.w);
            *(ushort4*)(lA + r * LDA + acol) = s;
        }
        #pragma unroll
        for (int p = 0; p < 4; p++) {
            int r = p * 32 + brow;
            bf16x8 v = *(const bf16x8*)(wxT + (size_t)(nbase + r) * KDIM + kb + bcol);
            *(bf16x8*)(lB + r * LDA + bcol) = v;
        }
        __syncthreads();
        #pragma unroll
        for (int kk = 0; kk < 2; kk++) {
            bf16x8 af[4], bfr[4];
            #pragma unroll
            for (int mt = 0; mt < 4; mt++)
                af[mt] = *(const bf16x8*)(lA + (wm + mt*16 + l16) * LDA + kk*32 + lhi*8);
            #pragma unroll
            for (int nt = 0; nt < 4; nt++)
                bfr[nt] = *(const bf16x8*)(lB + (wn + nt*16 + l16) * LDA + kk*32 + lhi*8);
            #pragma unroll
            for (int mt = 0; mt < 4; mt++)
                #pragma unroll
                for (int nt = 0; nt < 4; nt++)
                    acc[mt][nt] = __builtin_amdgcn_mfma_f32_16x16x32_bf16(
                        af[mt], bfr[nt], acc[mt][nt], 0, 0, 0);
        }
    }
    // epilogue: C/D layout col=lane&15 (N), row=(lane>>4)*4+i (M)
    #pragma unroll
    for (int nt = 0; nt < 4; nt++) {
        int n = nbase + wn + nt*16 + l16;
        float bv = biasx[n];
        int g = n >> 10;
        int j = n & 1023;
        float* outp = (g == 0) ? ggr : (g == 1) ? ggz : ggn;
        #pragma unroll
        for (int mt = 0; mt < 4; mt++) {
            #pragma unroll
            for (int i = 0; i < 4; i++) {
                int R = rbase + wm + mt*16 + lhi*4 + i;        // R = b*512 + t
                size_t orow = (size_t)((R & 511) * BATCH + (R >> 9));
                outp[orow * HID + j] = acc[mt][nt][i] + bv;
            }
        }
    }
}

// ---------------------------------------------------------------------------
// Recurrence v6: v5's latency-lean publish path + the race fix.
//
// v5 failed absmax 0.0215 (vs thresh 0.0185) with BIT-IDENTICAL arithmetic
// to the passing v4 -> a rare stale-h read.  Root cause: v5 relied on
// __syncthreads' implicit vmcnt drain to order waves 1-3's h stores before
// wave 0's flag fan-out, but s_barrier is an EXECUTION barrier; the memory
// legalizer does not drain relaxed agent-scope stores at it.  Fix: explicit
// per-wave s_waitcnt vmcnt(0) immediately before barrier 2 (each wave drains
// its own 2B h stores in parallel; nothing else is outstanding there -- the
// deferred dout/gate ops are a full iteration old).  This is v4's proven
// ordering, parallelized.
//
// Kept from v5: per-thread 2B h publish (no LDS pack), replicated private
// poll lines flags2[grp][consumer][producer], gate prefetch + dout store
// deferred AFTER the flag publish, sched_barrier(0) poll pin.
// ---------------------------------------------------------------------------
__global__ __launch_bounds__(256, 1) void k_recur(
    const float* __restrict__ ggr, const float* __restrict__ ggz,
    float* __restrict__ dout,                // [T][B][H] (gn preloaded) + tail [B][H]
    const unsigned short* __restrict__ whT,  // [3072][1024] bf16
    const float* __restrict__ biash,         // [3072]
    unsigned short* __restrict__ hbf,        // [2][64][1024] bf16
    int* __restrict__ flags2,                // [8][32 consumers][32 producers]
    int* __restrict__ gcnt)                  // global rank counter
{
    __shared__ f32x4 red[6 * 4 * 64];            // 24 KB: (gate*2+ct), wave, lane
    __shared__ int shr[1];

    int tid  = threadIdx.x;
    if (tid == 0) shr[0] = atomicAdd(gcnt, 1);
    __syncthreads();
    int grank = shr[0];
    int grp   = (grank >> 5) & 7;  // batch-row group (rows 8g..8g+8)
    int rank  = grank & 31;        // column group (cols 32r..32r+32)

    int w    = tid >> 6, lane = tid & 63;
    int l16  = lane & 15, lhi = lane >> 4;
    int row  = tid >> 5;           // epilogue row 0..7  (batch within group)
    int col  = tid & 31;           // epilogue col 0..31
    int colbase = rank * 32;
    int b_t  = grp * 8 + row;      // epilogue thread's batch row
    int j_t  = colbase + col;      // epilogue thread's column
    int hrow = grp * 8 + (l16 & 7);// mfma A-row (rows 8..15 duplicate 0..7)
    int kbase = w * 256 + lhi * 8; // this lane's K base

    // loop-invariant weight fragments: 2 col-tiles x 3 gates x 8 kk = 192 VGPR
    bf16x8 wf[2][3][8];
    #pragma unroll
    for (int ct = 0; ct < 2; ct++)
        #pragma unroll
        for (int g = 0; g < 3; g++) {
            const unsigned short* base =
                whT + (size_t)(g * HID + colbase + ct * 16 + l16) * KDIM + kbase;
            #pragma unroll
            for (int kk = 0; kk < 8; kk++)
                wf[ct][g][kk] = *(const bf16x8*)(base + kk * 32);
        }
    // pin: def becomes non-rematerializable asm -> stays resident (AGPR/VGPR)
    #pragma unroll
    for (int ct = 0; ct < 2; ct++)
        #pragma unroll
        for (int g = 0; g < 3; g++)
            #pragma unroll
            for (int kk = 0; kk < 8; kk++)
                asm volatile("" : "+v"(wf[ct][g][kk]));

    float bhr = biash[j_t], bhz = biash[HID + j_t], bhn = biash[2*HID + j_t];

    float hp = 0.f;
    float cgr, cgz, cgn;
    {
        size_t g0 = (size_t)b_t * HID + j_t;    // t = 0
        cgr = ggr[g0]; cgz = ggz[g0]; cgn = dout[g0];
    }

    // private poll line: this block's row of flags2, producer = w*8 + (lane&7)
    int* pollp   = flags2 + ((size_t)(grp * 32 + rank) * 32) + w * 8 + (lane & 7);
    int* flagrow = flags2 + (size_t)grp * 32 * 32;   // + consumer*32 + rank

    #pragma unroll 1
    for (int t = 0; t < TT; t++) {
        // ---- wait for step-t h from this wave's 8 same-group producers ----
        if (t > 0) {
            int guard = 0;
            bool ok;
            do {
                int f = __hip_atomic_load(pollp, __ATOMIC_RELAXED, __HIP_MEMORY_SCOPE_AGENT);
                ok = (f >= t);
            } while (!__all(ok) && ++guard < (1 << 17));
        }
        __builtin_amdgcn_sched_barrier(0);   // h loads stay after flag observation

        // ---- h loads: 8 rows x this wave's K-quarter, LLC (agent scope) ----
        const unsigned short* hb = hbf + (size_t)(t & 1) * BATCH * HID
                                 + (size_t)hrow * HID + kbase;
        unsigned long long hu[16];
        #pragma unroll
        for (int kk = 0; kk < 8; kk++) {
            hu[2*kk]   = __hip_atomic_load((unsigned long long*)(hb + kk*32),
                                           __ATOMIC_RELAXED, __HIP_MEMORY_SCOPE_AGENT);
            hu[2*kk+1] = __hip_atomic_load((unsigned long long*)(hb + kk*32) + 1,
                                           __ATOMIC_RELAXED, __HIP_MEMORY_SCOPE_AGENT);
        }

        // ---- partial GEMM over this wave's K-quarter: 2 col-tiles x 3 gates ----
        f32x4 acc[2][3];
        #pragma unroll
        for (int ct = 0; ct < 2; ct++)
            #pragma unroll
            for (int g = 0; g < 3; g++)
                acc[ct][g] = f32x4{0.f, 0.f, 0.f, 0.f};
        #pragma unroll
        for (int kk = 0; kk < 8; kk++) {
            union { unsigned long long u[2]; bf16x8 v; } fa;
            fa.u[0] = hu[2*kk]; fa.u[1] = hu[2*kk+1];
            #pragma unroll
            for (int ct = 0; ct < 2; ct++)
                #pragma unroll
                for (int g = 0; g < 3; g++)
                    acc[ct][g] = __builtin_amdgcn_mfma_f32_16x16x32_bf16(
                        fa.v, wf[ct][g][kk], acc[ct][g], 0, 0, 0);
        }

        // ---- cross-wave K reduction via LDS ----
        #pragma unroll
        for (int ct = 0; ct < 2; ct++)
            #pragma unroll
            for (int g = 0; g < 3; g++)
                red[((g * 2 + ct) * 4 + w) * 64 + lane] = acc[ct][g];
        __syncthreads();                                       // barrier 1
        int ctt = col >> 4, ri = row & 3;
        int lsrc = (row >> 2) * 16 + (col & 15);
        float s0 = 0.f, s1 = 0.f, s2 = 0.f;
        #pragma unroll
        for (int ww = 0; ww < 4; ww++) {
            s0 += red[((0 * 2 + ctt) * 4 + ww) * 64 + lsrc][ri];
            s1 += red[((1 * 2 + ctt) * 4 + ww) * 64 + lsrc][ri];
            s2 += red[((2 * 2 + ctt) * 4 + ww) * 64 + lsrc][ri];
        }

        // ---- epilogue: one element per thread ----
        float r  = 1.f / (1.f + __expf(-(cgr + s0 + bhr)));
        float z  = 1.f / (1.f + __expf(-(cgz + s1 + bhz)));
        float nv = cgn + r * (s2 + bhn);
        float th = 1.f - 2.f / (1.f + __expf(2.f * nv));   // tanh(nv)
        float hv = (1.f - z) * th + z * hp;
        hp = hv;
        if (t == TT - 1) {
            dout[((size_t)t * BATCH + b_t) * HID + j_t] = hv;
            dout[(size_t)TT * BATCH * HID + (size_t)b_t * HID + j_t] = hv;
            break;                                         // no one consumes next h
        }

        // ---- publish h: per-thread 2B agent store -> per-wave drain ->
        //      barrier -> fan-out flags ----
        {
            unsigned short* hdst = hbf + (size_t)((t + 1) & 1) * BATCH * HID
                                 + (size_t)b_t * HID + j_t;
            __hip_atomic_store(hdst, f2b(hv), __ATOMIC_RELAXED, __HIP_MEMORY_SCOPE_AGENT);
        }
        // RACE FIX (v5->v6): s_barrier alone does NOT drain relaxed stores.
        // Every wave acks its own h stores at the LLC before joining the
        // barrier; only then may wave 0 publish the flags.
        asm volatile("s_waitcnt vmcnt(0)" ::: "memory");
        __syncthreads();   // barrier 2
        if (tid < 32)      // one flag copy per consumer block of our group
            __hip_atomic_store(flagrow + tid * 32 + rank, t + 1,
                               __ATOMIC_RELAXED, __HIP_MEMORY_SCOPE_AGENT);

        // ---- deferred (off the critical path): dout store + gate prefetch ----
        dout[((size_t)t * BATCH + b_t) * HID + j_t] = hv;
        size_t g1 = (size_t)((t + 1) * BATCH + b_t) * HID + j_t;
        cgr = ggr[g1]; cgz = ggz[g1]; cgn = dout[g1];
    }
}

// ---------------------------------------------------------------------------
extern "C" void kernel_launch(void* const* d_in, const int* in_sizes, int n_in,
                              void* d_out, int out_size, void* d_ws, size_t ws_size,
                              hipStream_t stream)
{
    const float* x    = (const float*)d_in[0];
    const float* W_ir = (const float*)d_in[1];
    const float* b_ir = (const float*)d_in[2];
    const float* W_hr = (const float*)d_in[3];
    const float* b_hr = (const float*)d_in[4];
    const float* W_iz = (const float*)d_in[5];
    const float* b_iz = (const float*)d_in[6];
    const float* W_hz = (const float*)d_in[7];
    const float* b_hz = (const float*)d_in[8];
    const float* W_in = (const float*)d_in[9];
    const float* b_in = (const float*)d_in[10];
    const float* W_hn = (const float*)d_in[11];
    const float* b_hn = (const float*)d_in[12];
    float* out = (float*)d_out;

    char* ws = (char*)d_ws;
    size_t off = 0;
    auto alloc = [&](size_t bytes) -> char* {
        char* p = ws + off;
        off += (bytes + 255) & ~(size_t)255;
        return p;
    };
    float*          ggr      = (float*)alloc((size_t)TT * BATCH * HID * 4);
    float*          ggz      = (float*)alloc((size_t)TT * BATCH * HID * 4);
    unsigned short* wxT      = (unsigned short*)alloc((size_t)3 * HID * KDIM * 2);
    unsigned short* whT      = (unsigned short*)alloc((size_t)3 * HID * KDIM * 2);
    float*          bias_x   = (float*)alloc(3 * HID * 4);
    float*          bias_h   = (float*)alloc(3 * HID * 4);
    unsigned short* hbf      = (unsigned short*)alloc((size_t)2 * BATCH * HID * 2);
    int*            flags2   = (int*)alloc((size_t)8 * 32 * 32 * 4);
    int*            gcnt     = (int*)alloc(16 * 4);

    k_init<<<64, 256, 0, stream>>>(b_ir, b_iz, b_in, b_hr, b_hz, b_hn,
                                   bias_x, bias_h, hbf, flags2, gcnt);
    k_trans<<<dim3(32, 32, 6), dim3(32, 8), 0, stream>>>(W_ir, W_iz, W_in,
                                                         W_hr, W_hz, W_hn, wxT, whT);
    k_gemm_x<<<dim3(256, 24), 256, 0, stream>>>(x, wxT, bias_x, ggr, ggz, out);
    k_recur<<<256, 256, 0, stream>>>(ggr, ggz, out, whT, bias_h, hbf, flags2, gcnt);
}